// Round 1
// baseline (276.612 us; speedup 1.0000x reference)
//
#include <hip/hip_runtime.h>

#define DEVI __device__ __forceinline__

typedef __bf16 bf16x8 __attribute__((ext_vector_type(8)));
typedef float f32x4 __attribute__((ext_vector_type(4)));
typedef unsigned short u16x8 __attribute__((ext_vector_type(8)));

DEVI unsigned short f2bf(float f) {
  unsigned u = __builtin_bit_cast(unsigned, f);
  u += 0x7FFFu + ((u >> 16) & 1u);
  return (unsigned short)(u >> 16);
}
DEVI float bf2f(unsigned short h) {
  return __builtin_bit_cast(float, (unsigned)h << 16);
}

// ---------------- prep kernels ----------------

// x0 fp32 -> bf16, 8 elems/thread, 16.8M elems total
__global__ __launch_bounds__(256) void cast_x0_kernel(const float* __restrict__ x,
                                                      unsigned short* __restrict__ xb) {
  int i = blockIdx.x * 256 + threadIdx.x;  // i < 2097152
  const f32x4* p = (const f32x4*)x;
  f32x4 a = p[2 * i], b = p[2 * i + 1];
  u16x8 o;
  o[0] = f2bf(a[0]); o[1] = f2bf(a[1]); o[2] = f2bf(a[2]); o[3] = f2bf(a[3]);
  o[4] = f2bf(b[0]); o[5] = f2bf(b[1]); o[6] = f2bf(b[2]); o[7] = f2bf(b[3]);
  ((u16x8*)xb)[i] = o;
}

// U[L,E,D,R] -> W1T[l][n=e*64+r][k=d] bf16  (786432 elems)
__global__ __launch_bounds__(256) void pack_w1_kernel(const float* __restrict__ U,
                                                      unsigned short* __restrict__ W1T) {
  int idx = blockIdx.x * 256 + threadIdx.x;
  int l = idx >> 18;
  int rem = idx & 262143;
  int n = rem >> 10, k = rem & 1023;
  int e = n >> 6, r = n & 63;
  W1T[idx] = f2bf(U[(size_t)(((l * 4 + e) << 10) + k) * 64 + r]);
}

// V[L,E,R,D] -> V2T[l][d][c=e*64+r] bf16  (786432 elems)
__global__ __launch_bounds__(256) void pack_v2_kernel(const float* __restrict__ V,
                                                      unsigned short* __restrict__ V2T) {
  int idx = blockIdx.x * 256 + threadIdx.x;
  int l = idx >> 18;
  int rem = idx & 262143;
  int d = rem >> 8, c = rem & 255;
  int e = c >> 6, r = c & 63;
  V2T[idx] = f2bf(V[(size_t)(((l * 4 + e) * 64 + r) << 10) + d]);
}

// ---------------- gate: softmax(x @ gW + gb), one wave per row ----------------
__global__ __launch_bounds__(256) void gate_kernel(const unsigned short* __restrict__ xb,
                                                   const float* __restrict__ gWl,
                                                   const float* __restrict__ gbl,
                                                   float* __restrict__ gate) {
  int wid = threadIdx.x >> 6, lane = threadIdx.x & 63;
  int row = blockIdx.x * 4 + wid;
  const unsigned short* xr = xb + (size_t)row * 1024;
  float a0 = 0.f, a1 = 0.f, a2 = 0.f, a3 = 0.f;
#pragma unroll
  for (int j = 0; j < 16; ++j) {
    int d = j * 64 + lane;
    float xf = bf2f(xr[d]);
    f32x4 g = *(const f32x4*)(gWl + d * 4);
    a0 += xf * g[0]; a1 += xf * g[1]; a2 += xf * g[2]; a3 += xf * g[3];
  }
#pragma unroll
  for (int off = 32; off; off >>= 1) {
    a0 += __shfl_xor(a0, off);
    a1 += __shfl_xor(a1, off);
    a2 += __shfl_xor(a2, off);
    a3 += __shfl_xor(a3, off);
  }
  if (lane == 0) {
    a0 += gbl[0]; a1 += gbl[1]; a2 += gbl[2]; a3 += gbl[3];
    float m = fmaxf(fmaxf(a0, a1), fmaxf(a2, a3));
    float e0 = __expf(a0 - m), e1 = __expf(a1 - m), e2 = __expf(a2 - m), e3 = __expf(a3 - m);
    float inv = 1.0f / (e0 + e1 + e2 + e3);
    f32x4 o = {e0 * inv, e1 * inv, e2 * inv, e3 * inv};
    *(f32x4*)(gate + row * 4) = o;
  }
}

// ---------------- GEMM1: [16384,1024] x [1024,256] -> relu*gate -> hg bf16 ----------------
// BM=64 BN=128 BK=64, 256 threads (4 waves 2x2), wave tile 32x64 (2x4 16x16 frags)
__global__ __launch_bounds__(256) void k1_kernel(const unsigned short* __restrict__ A,
                                                 const unsigned short* __restrict__ Bw,
                                                 const float* __restrict__ gate,
                                                 unsigned short* __restrict__ Hg) {
  constexpr int K = 1024;
  __shared__ unsigned short As[64 * 64];
  __shared__ unsigned short Bs[128 * 64];
  int t = threadIdx.x;
  int wid = t >> 6, lane = t & 63;
  int wm = wid >> 1, wn = wid & 1;
  int m0 = blockIdx.x * 64;
  int n0 = blockIdx.y * 128;

  f32x4 acc[2][4];
#pragma unroll
  for (int m = 0; m < 2; ++m)
#pragma unroll
    for (int n = 0; n < 4; ++n) { f32x4 z = {0.f, 0.f, 0.f, 0.f}; acc[m][n] = z; }

  int arow = t >> 3;         // 0..31
  int acol = (t & 7) * 8;    // element offset within row

  for (int ks = 0; ks < K; ks += 64) {
    __syncthreads();
#pragma unroll
    for (int i = 0; i < 2; ++i) {
      const unsigned short* src = A + (size_t)(m0 + i * 32 + arow) * K + ks + acol;
      __builtin_amdgcn_global_load_lds((const __attribute__((address_space(1))) void*)src,
                                       (__attribute__((address_space(3))) void*)((char*)As + i * 4096 + wid * 1024),
                                       16, 0, 0);
    }
#pragma unroll
    for (int i = 0; i < 4; ++i) {
      const unsigned short* src = Bw + (size_t)(n0 + i * 32 + arow) * K + ks + acol;
      __builtin_amdgcn_global_load_lds((const __attribute__((address_space(1))) void*)src,
                                       (__attribute__((address_space(3))) void*)((char*)Bs + i * 4096 + wid * 1024),
                                       16, 0, 0);
    }
    __syncthreads();
#pragma unroll
    for (int kk = 0; kk < 2; ++kk) {
      bf16x8 af[2], bfr[4];
#pragma unroll
      for (int m = 0; m < 2; ++m)
        af[m] = *(const bf16x8*)(As + (wm * 32 + m * 16 + (lane & 15)) * 64 + kk * 32 + (lane >> 4) * 8);
#pragma unroll
      for (int n = 0; n < 4; ++n)
        bfr[n] = *(const bf16x8*)(Bs + (wn * 64 + n * 16 + (lane & 15)) * 64 + kk * 32 + (lane >> 4) * 8);
#pragma unroll
      for (int m = 0; m < 2; ++m)
#pragma unroll
        for (int n = 0; n < 4; ++n)
          acc[m][n] = __builtin_amdgcn_mfma_f32_16x16x32_bf16(af[m], bfr[n], acc[m][n], 0, 0, 0);
    }
  }

#pragma unroll
  for (int m = 0; m < 2; ++m) {
#pragma unroll
    for (int n = 0; n < 4; ++n) {
      int gc = n0 + wn * 64 + n * 16 + (lane & 15);
      int e = gc >> 6;
#pragma unroll
      for (int j = 0; j < 4; ++j) {
        int gr = m0 + wm * 32 + m * 16 + (lane >> 4) * 4 + j;
        float v = fmaxf(acc[m][n][j], 0.f) * gate[gr * 4 + e];
        Hg[(size_t)gr * 256 + gc] = f2bf(v);
      }
    }
  }
}

// ---------------- GEMM2: [16384,256] x [256,1024] -> residual mix epilogue ----------------
__global__ __launch_bounds__(256) void k2_kernel(const unsigned short* __restrict__ A,
                                                 const unsigned short* __restrict__ Bw,
                                                 const float* __restrict__ x0,
                                                 const float* __restrict__ xin,
                                                 const float* __restrict__ biasl,
                                                 float* __restrict__ out,
                                                 unsigned short* __restrict__ xbnext,
                                                 int write_bf) {
  constexpr int K = 256;
  __shared__ unsigned short As[64 * 64];
  __shared__ unsigned short Bs[128 * 64];
  int t = threadIdx.x;
  int wid = t >> 6, lane = t & 63;
  int wm = wid >> 1, wn = wid & 1;
  int m0 = blockIdx.x * 64;
  int n0 = blockIdx.y * 128;

  f32x4 acc[2][4];
#pragma unroll
  for (int m = 0; m < 2; ++m)
#pragma unroll
    for (int n = 0; n < 4; ++n) { f32x4 z = {0.f, 0.f, 0.f, 0.f}; acc[m][n] = z; }

  int arow = t >> 3;
  int acol = (t & 7) * 8;

  for (int ks = 0; ks < K; ks += 64) {
    __syncthreads();
#pragma unroll
    for (int i = 0; i < 2; ++i) {
      const unsigned short* src = A + (size_t)(m0 + i * 32 + arow) * K + ks + acol;
      __builtin_amdgcn_global_load_lds((const __attribute__((address_space(1))) void*)src,
                                       (__attribute__((address_space(3))) void*)((char*)As + i * 4096 + wid * 1024),
                                       16, 0, 0);
    }
#pragma unroll
    for (int i = 0; i < 4; ++i) {
      const unsigned short* src = Bw + (size_t)(n0 + i * 32 + arow) * K + ks + acol;
      __builtin_amdgcn_global_load_lds((const __attribute__((address_space(1))) void*)src,
                                       (__attribute__((address_space(3))) void*)((char*)Bs + i * 4096 + wid * 1024),
                                       16, 0, 0);
    }
    __syncthreads();
#pragma unroll
    for (int kk = 0; kk < 2; ++kk) {
      bf16x8 af[2], bfr[4];
#pragma unroll
      for (int m = 0; m < 2; ++m)
        af[m] = *(const bf16x8*)(As + (wm * 32 + m * 16 + (lane & 15)) * 64 + kk * 32 + (lane >> 4) * 8);
#pragma unroll
      for (int n = 0; n < 4; ++n)
        bfr[n] = *(const bf16x8*)(Bs + (wn * 64 + n * 16 + (lane & 15)) * 64 + kk * 32 + (lane >> 4) * 8);
#pragma unroll
      for (int m = 0; m < 2; ++m)
#pragma unroll
        for (int n = 0; n < 4; ++n)
          acc[m][n] = __builtin_amdgcn_mfma_f32_16x16x32_bf16(af[m], bfr[n], acc[m][n], 0, 0, 0);
    }
  }

#pragma unroll
  for (int m = 0; m < 2; ++m) {
#pragma unroll
    for (int n = 0; n < 4; ++n) {
      int gc = n0 + wn * 64 + n * 16 + (lane & 15);
      float bv = biasl[gc];
#pragma unroll
      for (int j = 0; j < 4; ++j) {
        int gr = m0 + wm * 32 + m * 16 + (lane >> 4) * 4 + j;
        size_t off = (size_t)gr * 1024 + gc;
        float res = x0[off] * acc[m][n][j] + bv + xin[off];
        out[off] = res;
        if (write_bf) xbnext[off] = f2bf(res);
      }
    }
  }
}

// ---------------- host ----------------
extern "C" void kernel_launch(void* const* d_in, const int* in_sizes, int n_in,
                              void* d_out, int out_size, void* d_ws, size_t ws_size,
                              hipStream_t stream) {
  const float* x0 = (const float*)d_in[0];
  const float* U = (const float*)d_in[1];
  const float* V = (const float*)d_in[2];
  const float* gW = (const float*)d_in[3];
  const float* gb = (const float*)d_in[4];
  const float* bias = (const float*)d_in[5];
  float* out = (float*)d_out;
  char* ws = (char*)d_ws;

  // ws layout (bytes)
  unsigned short* xbf = (unsigned short*)(ws);               // 33554432
  unsigned short* hg = (unsigned short*)(ws + 33554432);     // 8388608
  float* gate = (float*)(ws + 41943040);                     // 262144
  unsigned short* W1T = (unsigned short*)(ws + 42205184);    // 1572864
  unsigned short* V2T = (unsigned short*)(ws + 43778048);    // 1572864

  cast_x0_kernel<<<8192, 256, 0, stream>>>(x0, xbf);
  pack_w1_kernel<<<3072, 256, 0, stream>>>(U, W1T);
  pack_v2_kernel<<<3072, 256, 0, stream>>>(V, V2T);

  for (int l = 0; l < 3; ++l) {
    const float* xin = (l == 0) ? x0 : out;
    gate_kernel<<<4096, 256, 0, stream>>>(xbf, gW + l * 4096, gb + l * 4, gate);
    k1_kernel<<<dim3(256, 2), 256, 0, stream>>>(xbf, W1T + l * 262144, gate, hg);
    k2_kernel<<<dim3(256, 8), 256, 0, stream>>>(hg, V2T + l * 262144, x0, xin,
                                                bias + l * 1024, out, xbf, (l < 2) ? 1 : 0);
  }
}

// Round 2
// 253.096 us; speedup vs baseline: 1.0929x; 1.0929x over previous
//
#include <hip/hip_runtime.h>

#define DEVI __device__ __forceinline__

typedef __bf16 bf16x8 __attribute__((ext_vector_type(8)));
typedef float f32x4 __attribute__((ext_vector_type(4)));
typedef unsigned short u16x8 __attribute__((ext_vector_type(8)));

DEVI unsigned short f2bf(float f) {
  unsigned u = __builtin_bit_cast(unsigned, f);
  u += 0x7FFFu + ((u >> 16) & 1u);
  return (unsigned short)(u >> 16);
}
DEVI float bf2f(unsigned short h) {
  return __builtin_bit_cast(float, (unsigned)h << 16);
}

// ---------------- prep kernels ----------------

// x0 fp32 -> bf16, 8 elems/thread
__global__ __launch_bounds__(256) void cast_x0_kernel(const float* __restrict__ x,
                                                      unsigned short* __restrict__ xb) {
  int i = blockIdx.x * 256 + threadIdx.x;  // i < 2097152
  const f32x4* p = (const f32x4*)x;
  f32x4 a = p[2 * i], b = p[2 * i + 1];
  u16x8 o;
  o[0] = f2bf(a[0]); o[1] = f2bf(a[1]); o[2] = f2bf(a[2]); o[3] = f2bf(a[3]);
  o[4] = f2bf(b[0]); o[5] = f2bf(b[1]); o[6] = f2bf(b[2]); o[7] = f2bf(b[3]);
  ((u16x8*)xb)[i] = o;
}

// U[L,E,D,R] -> W1T[l][n=e*64+r][k=d] bf16
__global__ __launch_bounds__(256) void pack_w1_kernel(const float* __restrict__ U,
                                                      unsigned short* __restrict__ W1T) {
  int idx = blockIdx.x * 256 + threadIdx.x;
  int l = idx >> 18;
  int rem = idx & 262143;
  int n = rem >> 10, k = rem & 1023;
  int e = n >> 6, r = n & 63;
  W1T[idx] = f2bf(U[(size_t)(((l * 4 + e) << 10) + k) * 64 + r]);
}

// V[L,E,R,D] -> V2T[l][d][c=e*64+r] bf16
__global__ __launch_bounds__(256) void pack_v2_kernel(const float* __restrict__ V,
                                                      unsigned short* __restrict__ V2T) {
  int idx = blockIdx.x * 256 + threadIdx.x;
  int l = idx >> 18;
  int rem = idx & 262143;
  int d = rem >> 8, c = rem & 255;
  int e = c >> 6, r = c & 63;
  V2T[idx] = f2bf(V[(size_t)(((l * 4 + e) * 64 + r) << 10) + d]);
}

// ---------------- gate: softmax(x @ gW + gb), one wave per row ----------------
__global__ __launch_bounds__(256) void gate_kernel(const unsigned short* __restrict__ xb,
                                                   const float* __restrict__ gWl,
                                                   const float* __restrict__ gbl,
                                                   float* __restrict__ gate) {
  int wid = threadIdx.x >> 6, lane = threadIdx.x & 63;
  int row = blockIdx.x * 4 + wid;
  const unsigned short* xr = xb + (size_t)row * 1024;
  float a0 = 0.f, a1 = 0.f, a2 = 0.f, a3 = 0.f;
#pragma unroll
  for (int j = 0; j < 16; ++j) {
    int d = j * 64 + lane;
    float xf = bf2f(xr[d]);
    f32x4 g = *(const f32x4*)(gWl + d * 4);
    a0 += xf * g[0]; a1 += xf * g[1]; a2 += xf * g[2]; a3 += xf * g[3];
  }
#pragma unroll
  for (int off = 32; off; off >>= 1) {
    a0 += __shfl_xor(a0, off);
    a1 += __shfl_xor(a1, off);
    a2 += __shfl_xor(a2, off);
    a3 += __shfl_xor(a3, off);
  }
  if (lane == 0) {
    a0 += gbl[0]; a1 += gbl[1]; a2 += gbl[2]; a3 += gbl[3];
    float m = fmaxf(fmaxf(a0, a1), fmaxf(a2, a3));
    float e0 = __expf(a0 - m), e1 = __expf(a1 - m), e2 = __expf(a2 - m), e3 = __expf(a3 - m);
    float inv = 1.0f / (e0 + e1 + e2 + e3);
    f32x4 o = {e0 * inv, e1 * inv, e2 * inv, e3 * inv};
    *(f32x4*)(gate + row * 4) = o;
  }
}

// ---------------- GEMM1: [16384,1024] x [1024,256] -> relu*gate -> hg bf16 ----------------
__global__ __launch_bounds__(256) void k1_kernel(const unsigned short* __restrict__ A,
                                                 const unsigned short* __restrict__ Bw,
                                                 const float* __restrict__ gate,
                                                 unsigned short* __restrict__ Hg) {
  constexpr int K = 1024;
  __shared__ unsigned short As[64 * 64];
  __shared__ unsigned short Bs[128 * 64];
  int t = threadIdx.x;
  int wid = t >> 6, lane = t & 63;
  int wm = wid >> 1, wn = wid & 1;
  int m0 = blockIdx.x * 64;
  int n0 = blockIdx.y * 128;

  f32x4 acc[2][4];
#pragma unroll
  for (int m = 0; m < 2; ++m)
#pragma unroll
    for (int n = 0; n < 4; ++n) { f32x4 z = {0.f, 0.f, 0.f, 0.f}; acc[m][n] = z; }

  int arow = t >> 3;
  int acol = (t & 7) * 8;

  for (int ks = 0; ks < K; ks += 64) {
    __syncthreads();
#pragma unroll
    for (int i = 0; i < 2; ++i) {
      const unsigned short* src = A + (size_t)(m0 + i * 32 + arow) * K + ks + acol;
      __builtin_amdgcn_global_load_lds((const __attribute__((address_space(1))) void*)src,
                                       (__attribute__((address_space(3))) void*)((char*)As + i * 4096 + wid * 1024),
                                       16, 0, 0);
    }
#pragma unroll
    for (int i = 0; i < 4; ++i) {
      const unsigned short* src = Bw + (size_t)(n0 + i * 32 + arow) * K + ks + acol;
      __builtin_amdgcn_global_load_lds((const __attribute__((address_space(1))) void*)src,
                                       (__attribute__((address_space(3))) void*)((char*)Bs + i * 4096 + wid * 1024),
                                       16, 0, 0);
    }
    __syncthreads();
#pragma unroll
    for (int kk = 0; kk < 2; ++kk) {
      bf16x8 af[2], bfr[4];
#pragma unroll
      for (int m = 0; m < 2; ++m)
        af[m] = *(const bf16x8*)(As + (wm * 32 + m * 16 + (lane & 15)) * 64 + kk * 32 + (lane >> 4) * 8);
#pragma unroll
      for (int n = 0; n < 4; ++n)
        bfr[n] = *(const bf16x8*)(Bs + (wn * 64 + n * 16 + (lane & 15)) * 64 + kk * 32 + (lane >> 4) * 8);
#pragma unroll
      for (int m = 0; m < 2; ++m)
#pragma unroll
        for (int n = 0; n < 4; ++n)
          acc[m][n] = __builtin_amdgcn_mfma_f32_16x16x32_bf16(af[m], bfr[n], acc[m][n], 0, 0, 0);
    }
  }

#pragma unroll
  for (int m = 0; m < 2; ++m) {
#pragma unroll
    for (int n = 0; n < 4; ++n) {
      int gc = n0 + wn * 64 + n * 16 + (lane & 15);
      int e = gc >> 6;
#pragma unroll
      for (int j = 0; j < 4; ++j) {
        int gr = m0 + wm * 32 + m * 16 + (lane >> 4) * 4 + j;
        float v = fmaxf(acc[m][n][j], 0.f) * gate[gr * 4 + e];
        Hg[(size_t)gr * 256 + gc] = f2bf(v);
      }
    }
  }
}

// ---------------- GEMM2: [16384,256] x [256,1024] -> residual mix epilogue ----------------
// Epilogue: res = x0*acc + bias + x_cur (x_cur bf16, in-place safe: same thread RW)
__global__ __launch_bounds__(256) void k2_kernel(const unsigned short* __restrict__ A,
                                                 const unsigned short* __restrict__ Bw,
                                                 const float* __restrict__ x0,
                                                 const unsigned short* __restrict__ xcur,
                                                 const float* __restrict__ biasl,
                                                 unsigned short* __restrict__ xnext,
                                                 float* __restrict__ out,
                                                 int last) {
  constexpr int K = 256;
  __shared__ unsigned short As[64 * 64];
  __shared__ unsigned short Bs[128 * 64];
  int t = threadIdx.x;
  int wid = t >> 6, lane = t & 63;
  int wm = wid >> 1, wn = wid & 1;
  int m0 = blockIdx.x * 64;
  int n0 = blockIdx.y * 128;

  f32x4 acc[2][4];
#pragma unroll
  for (int m = 0; m < 2; ++m)
#pragma unroll
    for (int n = 0; n < 4; ++n) { f32x4 z = {0.f, 0.f, 0.f, 0.f}; acc[m][n] = z; }

  int arow = t >> 3;
  int acol = (t & 7) * 8;

  for (int ks = 0; ks < K; ks += 64) {
    __syncthreads();
#pragma unroll
    for (int i = 0; i < 2; ++i) {
      const unsigned short* src = A + (size_t)(m0 + i * 32 + arow) * K + ks + acol;
      __builtin_amdgcn_global_load_lds((const __attribute__((address_space(1))) void*)src,
                                       (__attribute__((address_space(3))) void*)((char*)As + i * 4096 + wid * 1024),
                                       16, 0, 0);
    }
#pragma unroll
    for (int i = 0; i < 4; ++i) {
      const unsigned short* src = Bw + (size_t)(n0 + i * 32 + arow) * K + ks + acol;
      __builtin_amdgcn_global_load_lds((const __attribute__((address_space(1))) void*)src,
                                       (__attribute__((address_space(3))) void*)((char*)Bs + i * 4096 + wid * 1024),
                                       16, 0, 0);
    }
    __syncthreads();
#pragma unroll
    for (int kk = 0; kk < 2; ++kk) {
      bf16x8 af[2], bfr[4];
#pragma unroll
      for (int m = 0; m < 2; ++m)
        af[m] = *(const bf16x8*)(As + (wm * 32 + m * 16 + (lane & 15)) * 64 + kk * 32 + (lane >> 4) * 8);
#pragma unroll
      for (int n = 0; n < 4; ++n)
        bfr[n] = *(const bf16x8*)(Bs + (wn * 64 + n * 16 + (lane & 15)) * 64 + kk * 32 + (lane >> 4) * 8);
#pragma unroll
      for (int m = 0; m < 2; ++m)
#pragma unroll
        for (int n = 0; n < 4; ++n)
          acc[m][n] = __builtin_amdgcn_mfma_f32_16x16x32_bf16(af[m], bfr[n], acc[m][n], 0, 0, 0);
    }
  }

#pragma unroll
  for (int m = 0; m < 2; ++m) {
#pragma unroll
    for (int n = 0; n < 4; ++n) {
      int gc = n0 + wn * 64 + n * 16 + (lane & 15);
      float bv = biasl[gc];
#pragma unroll
      for (int j = 0; j < 4; ++j) {
        int gr = m0 + wm * 32 + m * 16 + (lane >> 4) * 4 + j;
        size_t off = (size_t)gr * 1024 + gc;
        float res = x0[off] * acc[m][n][j] + bv + bf2f(xcur[off]);
        if (last) out[off] = res;
        else xnext[off] = f2bf(res);
      }
    }
  }
}

// ---------------- host ----------------
extern "C" void kernel_launch(void* const* d_in, const int* in_sizes, int n_in,
                              void* d_out, int out_size, void* d_ws, size_t ws_size,
                              hipStream_t stream) {
  const float* x0 = (const float*)d_in[0];
  const float* U = (const float*)d_in[1];
  const float* V = (const float*)d_in[2];
  const float* gW = (const float*)d_in[3];
  const float* gb = (const float*)d_in[4];
  const float* bias = (const float*)d_in[5];
  float* out = (float*)d_out;
  char* ws = (char*)d_ws;

  // ws layout (bytes) — 45.3 MB total (same footprint as the passing R0)
  unsigned short* xbf = (unsigned short*)(ws);               // 33554432
  unsigned short* hg = (unsigned short*)(ws + 33554432);     // 8388608
  float* gate = (float*)(ws + 41943040);                     // 262144
  unsigned short* W1T = (unsigned short*)(ws + 42205184);    // 1572864
  unsigned short* V2T = (unsigned short*)(ws + 43778048);    // 1572864

  cast_x0_kernel<<<8192, 256, 0, stream>>>(x0, xbf);
  pack_w1_kernel<<<3072, 256, 0, stream>>>(U, W1T);
  pack_v2_kernel<<<3072, 256, 0, stream>>>(V, V2T);

  for (int l = 0; l < 3; ++l) {
    gate_kernel<<<4096, 256, 0, stream>>>(xbf, gW + l * 4096, gb + l * 4, gate);
    k1_kernel<<<dim3(256, 2), 256, 0, stream>>>(xbf, W1T + l * 262144, gate, hg);
    k2_kernel<<<dim3(256, 8), 256, 0, stream>>>(hg, V2T + l * 262144, x0, xbf,
                                                bias + l * 1024, xbf, out, (l == 2) ? 1 : 0);
  }
}